// Round 1
// baseline (2901.538 us; speedup 1.0000x reference)
//
#include <hip/hip_runtime.h>

#define D_IN 128
#define D_OUT 64

// ---------------------------------------------------------------------------
// 1) Degree histogram over edge targets (self-loop added later as +1).
// ---------------------------------------------------------------------------
__global__ void k_count(const int* __restrict__ row, unsigned int* __restrict__ deg, int E) {
    int e = blockIdx.x * blockDim.x + threadIdx.x;
    if (e < E) atomicAdd(&deg[row[e]], 1u);
}

// ---------------------------------------------------------------------------
// 2) dinv[i] = rsqrt(deg[i] + 1)   (deg >= 0, +1 self-loop => always > 0)
// ---------------------------------------------------------------------------
__global__ void k_rsqrt(const unsigned int* __restrict__ deg, float* __restrict__ dinv, int n) {
    int i = blockIdx.x * blockDim.x + threadIdx.x;
    if (i < n) dinv[i] = rsqrtf((float)(deg[i] + 1u));
}

// ---------------------------------------------------------------------------
// 3) h_scaled[i][:] = dinv[i] * (x[i] @ W); accum[i][:] = h_scaled[i][:]
//    One wave per node: lane j computes output feature j (64 lanes = 64 feats).
//    W (128x64 f32 = 32 KB) staged in LDS once per block; x row staged in a
//    per-wave LDS buffer (wave-synchronous, in-order LDS => no barrier needed).
// ---------------------------------------------------------------------------
__global__ __launch_bounds__(256) void k_gemm(
    const float* __restrict__ x, const float* __restrict__ W,
    const float* __restrict__ dinv, float* __restrict__ h,
    float* __restrict__ accum, int n) {
    __shared__ float Ws[D_IN * D_OUT];   // [k][j], 32 KB
    __shared__ float xs[4][D_IN];        // per-wave x row
    for (int idx = threadIdx.x; idx < D_IN * D_OUT; idx += 256)
        Ws[idx] = W[idx];
    __syncthreads();

    const int wave = threadIdx.x >> 6;
    const int lane = threadIdx.x & 63;

    for (int i = blockIdx.x * 4 + wave; i < n; i += gridDim.x * 4) {
        // stage x row: 64 lanes x float2 = 128 floats
        float2 v = *(const float2*)(&x[(size_t)i * D_IN + lane * 2]);
        *(float2*)(&xs[wave][lane * 2]) = v;
        // wave64 lockstep + in-order LDS per wave: reads below see the writes
        float acc = 0.f;
#pragma unroll
        for (int k = 0; k < D_IN; ++k)
            acc = fmaf(xs[wave][k], Ws[k * D_OUT + lane], acc);
        float s = dinv[i] * acc;
        h[(size_t)i * D_OUT + lane] = s;      // scaled transform
        accum[(size_t)i * D_OUT + lane] = s;  // seed with self-loop term
    }
}

// ---------------------------------------------------------------------------
// 4) Edge scatter: accum[row] += h_scaled[col].  16 threads per edge,
//    float4 gather + 4 native fp32 atomics.
// ---------------------------------------------------------------------------
__global__ void k_scatter(const int* __restrict__ row, const int* __restrict__ col,
                          const float* __restrict__ h, float* __restrict__ accum, int E) {
    int t = blockIdx.x * blockDim.x + threadIdx.x;
    int e = t >> 4;
    if (e >= E) return;
    int f = (t & 15) * 4;
    int r = row[e];
    int c = col[e];
    const float4 v = *(const float4*)(&h[(size_t)c * D_OUT + f]);
    float* dst = &accum[(size_t)r * D_OUT + f];
    unsafeAtomicAdd(dst + 0, v.x);
    unsafeAtomicAdd(dst + 1, v.y);
    unsafeAtomicAdd(dst + 2, v.z);
    unsafeAtomicAdd(dst + 3, v.w);
}

// ---------------------------------------------------------------------------
// 5) out[i][j] = relu(dinv[i] * accum[i][j] + b[j]), in place on d_out.
// ---------------------------------------------------------------------------
__global__ void k_final(float* __restrict__ out, const float* __restrict__ dinv,
                        const float* __restrict__ b, int n) {
    int t = blockIdx.x * blockDim.x + threadIdx.x;  // one float4 per thread
    if (t >= n * 16) return;
    int i = t >> 4;
    int j4 = t & 15;
    float4 v = *(float4*)(&out[(size_t)t * 4]);
    float4 bb = *(const float4*)(&b[j4 * 4]);
    float d = dinv[i];
    v.x = fmaxf(fmaf(d, v.x, bb.x), 0.f);
    v.y = fmaxf(fmaf(d, v.y, bb.y), 0.f);
    v.z = fmaxf(fmaf(d, v.z, bb.z), 0.f);
    v.w = fmaxf(fmaf(d, v.w, bb.w), 0.f);
    *(float4*)(&out[(size_t)t * 4]) = v;
}

extern "C" void kernel_launch(void* const* d_in, const int* in_sizes, int n_in,
                              void* d_out, int out_size, void* d_ws, size_t ws_size,
                              hipStream_t stream) {
    const float* x  = (const float*)d_in[0];
    const int*   ei = (const int*)d_in[1];   // [2][E] int32: row=targets, col=sources
    const float* W  = (const float*)d_in[2];
    const float* b  = (const float*)d_in[3];
    const int n = in_sizes[0] / D_IN;   // 100000
    const int E = in_sizes[1] / 2;      // 3200000
    const int* row = ei;
    const int* col = ei + E;

    // workspace layout (floats): [dinv: n][deg: n][h_scaled: n*64]  ~26.4 MB
    float*        dinv = (float*)d_ws;
    unsigned int* deg  = (unsigned int*)d_ws + n;
    float*        h    = (float*)d_ws + 2 * (size_t)n;
    float*        accum = (float*)d_out;

    hipMemsetAsync(deg, 0, (size_t)n * sizeof(unsigned int), stream);
    k_count<<<(E + 255) / 256, 256, 0, stream>>>(row, deg, E);
    k_rsqrt<<<(n + 255) / 256, 256, 0, stream>>>(deg, dinv, n);
    k_gemm<<<1024, 256, 0, stream>>>(x, W, dinv, h, accum, n);
    k_scatter<<<(E * 16 + 255) / 256, 256, 0, stream>>>(row, col, h, accum, E);
    k_final<<<(n * 16 + 255) / 256, 256, 0, stream>>>(accum, dinv, b, n);
}

// Round 2
// 644.509 us; speedup vs baseline: 4.5019x; 4.5019x over previous
//
#include <hip/hip_runtime.h>

#define D_IN 128
#define D_OUT 64

// --- bf16 helpers (round-to-nearest-even) ----------------------------------
__device__ inline float bf2f(unsigned short u) {
    union { unsigned int i; float f; } v; v.i = ((unsigned int)u) << 16; return v.f;
}
__device__ inline unsigned short f2bf(float f) {
    union { float f; unsigned int i; } v; v.f = f;
    unsigned int r = v.i + 0x7fffu + ((v.i >> 16) & 1u);
    return (unsigned short)(r >> 16);
}

// ---------------------------------------------------------------------------
// 1) Degree histogram over edge targets (int atomics, cheap).
// ---------------------------------------------------------------------------
__global__ void k_count(const int* __restrict__ row, unsigned int* __restrict__ deg, int E) {
    int e = blockIdx.x * blockDim.x + threadIdx.x;
    if (e < E) atomicAdd(&deg[row[e]], 1u);
}

// ---------------------------------------------------------------------------
// 2a) Per-block exclusive scan of deg -> row_ptr (partial), block sums out.
// ---------------------------------------------------------------------------
__global__ void k_scan1(const unsigned int* __restrict__ deg, int* __restrict__ excl,
                        int* __restrict__ bsums, int n) {
    __shared__ int tmp[256];
    int tid = threadIdx.x;
    int i = blockIdx.x * 256 + tid;
    int v = (i < n) ? (int)deg[i] : 0;
    tmp[tid] = v;
    __syncthreads();
    for (int off = 1; off < 256; off <<= 1) {
        int t = (tid >= off) ? tmp[tid - off] : 0;
        __syncthreads();
        tmp[tid] += t;
        __syncthreads();
    }
    if (i < n) excl[i] = tmp[tid] - v;           // exclusive within block
    if (tid == 255) bsums[blockIdx.x] = tmp[255]; // block total
}

// ---------------------------------------------------------------------------
// 2b) Exclusive scan of block sums (single block; requires nb <= 512).
// ---------------------------------------------------------------------------
__global__ void k_scan2(int* __restrict__ bsums, int nb) {
    __shared__ int tmp[512];
    int tid = threadIdx.x;
    int v = (tid < nb) ? bsums[tid] : 0;
    tmp[tid] = v;
    __syncthreads();
    for (int off = 1; off < 512; off <<= 1) {
        int t = (tid >= off) ? tmp[tid - off] : 0;
        __syncthreads();
        tmp[tid] += t;
        __syncthreads();
    }
    if (tid < nb) bsums[tid] = tmp[tid] - v;
}

// ---------------------------------------------------------------------------
// 2c) Add block offsets; init cursor copy; dinv = rsqrt(deg+1).
// ---------------------------------------------------------------------------
__global__ void k_scan3(int* __restrict__ row_ptr, const int* __restrict__ bsums,
                        int* __restrict__ cursor, const unsigned int* __restrict__ deg,
                        float* __restrict__ dinv, int n, int E) {
    int i = blockIdx.x * 256 + threadIdx.x;
    if (i < n) {
        int rp = row_ptr[i] + bsums[i >> 8];
        row_ptr[i] = rp;
        cursor[i] = rp;
        dinv[i] = rsqrtf((float)(deg[i] + 1u));
    }
    if (i == 0) row_ptr[n] = E;
}

// ---------------------------------------------------------------------------
// 3) h[i][:] = bf16( dinv[i] * (x[i] @ W) ).  One wave per node; lane j =
//    output feature j. W (32 KB) in LDS; x row staged per-wave (wave64
//    lockstep, in-order LDS -> no barrier needed).
// ---------------------------------------------------------------------------
__global__ __launch_bounds__(256) void k_gemm(
    const float* __restrict__ x, const float* __restrict__ W,
    const float* __restrict__ dinv, unsigned short* __restrict__ h, int n) {
    __shared__ float Ws[D_IN * D_OUT];   // [k][j], 32 KB
    __shared__ float xs[4][D_IN];
    for (int idx = threadIdx.x; idx < D_IN * D_OUT; idx += 256)
        Ws[idx] = W[idx];
    __syncthreads();

    const int wave = threadIdx.x >> 6;
    const int lane = threadIdx.x & 63;

    for (int i = blockIdx.x * 4 + wave; i < n; i += gridDim.x * 4) {
        float2 v = *(const float2*)(&x[(size_t)i * D_IN + lane * 2]);
        *(float2*)(&xs[wave][lane * 2]) = v;
        float acc = 0.f;
#pragma unroll
        for (int k = 0; k < D_IN; ++k)
            acc = fmaf(xs[wave][k], Ws[k * D_OUT + lane], acc);
        h[(size_t)i * D_OUT + lane] = f2bf(dinv[i] * acc);
    }
}

// ---------------------------------------------------------------------------
// 4) Counting-sort scatter: bucket source cols by target row.
// ---------------------------------------------------------------------------
__global__ void k_bucket(const int* __restrict__ row, const int* __restrict__ col,
                         int* __restrict__ cursor, int* __restrict__ scol, int E) {
    int e = blockIdx.x * blockDim.x + threadIdx.x;
    if (e >= E) return;
    int pos = atomicAdd(&cursor[row[e]], 1);
    scol[pos] = col[e];
}

// ---------------------------------------------------------------------------
// 5) Gather-reduce + finalize: one wave per node, lane j = feature j.
//    out[i][j] = relu( dinv[i] * (h[i][j] + sum_c h[c][j]) + b[j] )
// ---------------------------------------------------------------------------
__global__ __launch_bounds__(256) void k_aggr(
    const unsigned short* __restrict__ h, const int* __restrict__ row_ptr,
    const int* __restrict__ scol, const float* __restrict__ dinv,
    const float* __restrict__ b, float* __restrict__ out, int n) {
    const int wave = threadIdx.x >> 6;
    const int lane = threadIdx.x & 63;
    const int i = blockIdx.x * 4 + wave;
    if (i >= n) return;

    float acc = bf2f(h[(size_t)i * D_OUT + lane]);  // self-loop term
    const int beg = row_ptr[i];
    const int end = row_ptr[i + 1];
    for (int base = beg; base < end; base += 64) {
        const int m = min(64, end - base);
        const int c = (base + lane < end) ? scol[base + lane] : 0;
        for (int j = 0; j < m; ++j) {
            const int cj = __shfl(c, j);
            acc += bf2f(h[(size_t)cj * D_OUT + lane]);
        }
    }
    out[(size_t)i * D_OUT + lane] = fmaxf(fmaf(dinv[i], acc, b[lane]), 0.f);
}

extern "C" void kernel_launch(void* const* d_in, const int* in_sizes, int n_in,
                              void* d_out, int out_size, void* d_ws, size_t ws_size,
                              hipStream_t stream) {
    const float* x  = (const float*)d_in[0];
    const int*   ei = (const int*)d_in[1];   // [2][E] int32: row=targets, col=sources
    const float* W  = (const float*)d_in[2];
    const float* b  = (const float*)d_in[3];
    const int n = in_sizes[0] / D_IN;   // 100000
    const int E = in_sizes[1] / 2;      // 3200000
    const int* row = ei;
    const int* col = ei + E;

    // workspace layout (64B-aligned chunks), total ~27.3 MB
    char* base = (char*)d_ws;
    size_t off = 0;
    auto alloc = [&](size_t bytes) { char* p = base + off; off += (bytes + 63) & ~(size_t)63; return p; };
    unsigned short* h       = (unsigned short*)alloc((size_t)n * D_OUT * 2); // 12.8 MB
    int*            scol    = (int*)alloc((size_t)E * 4);                    // 12.8 MB
    unsigned int*   deg     = (unsigned int*)alloc((size_t)n * 4);
    int*            row_ptr = (int*)alloc(((size_t)n + 1) * 4);
    int*            cursor  = (int*)alloc((size_t)n * 4);
    float*          dinv    = (float*)alloc((size_t)n * 4);
    int*            bsums   = (int*)alloc(512 * 4);

    const int NB = (n + 255) / 256;  // 391 <= 512

    hipMemsetAsync(deg, 0, (size_t)n * sizeof(unsigned int), stream);
    k_count<<<(E + 255) / 256, 256, 0, stream>>>(row, deg, E);
    k_scan1<<<NB, 256, 0, stream>>>(deg, row_ptr, bsums, n);
    k_scan2<<<1, 512, 0, stream>>>(bsums, NB);
    k_scan3<<<NB, 256, 0, stream>>>(row_ptr, bsums, cursor, deg, dinv, n, E);
    k_gemm<<<1024, 256, 0, stream>>>(x, W, dinv, h, n);
    k_bucket<<<(E + 255) / 256, 256, 0, stream>>>(row, col, cursor, scol, E);
    k_aggr<<<(n + 3) / 4, 256, 0, stream>>>(h, row_ptr, scol, dinv, b, out_size ? (float*)d_out : (float*)d_out, n);
}

// Round 3
// 398.284 us; speedup vs baseline: 7.2851x; 1.6182x over previous
//
#include <hip/hip_runtime.h>

#define D_IN 128
#define D_OUT 64
#define NSLICE 8

// --- bf16 helpers (round-to-nearest-even) ----------------------------------
__device__ inline float bf2f(unsigned short u) {
    union { unsigned int i; float f; } v; v.i = ((unsigned int)u) << 16; return v.f;
}
__device__ inline unsigned short f2bf(float f) {
    union { float f; unsigned int i; } v; v.f = f;
    unsigned int r = v.i + 0x7fffu + ((v.i >> 16) & 1u);
    return (unsigned short)(r >> 16);
}

// ---------------------------------------------------------------------------
// 1) Degree histogram over edge targets (int atomics on L2-hot 400 KB).
// ---------------------------------------------------------------------------
__global__ void k_count(const int* __restrict__ row, unsigned int* __restrict__ deg, int E) {
    int e = blockIdx.x * blockDim.x + threadIdx.x;
    int stride = gridDim.x * blockDim.x;
    for (; e < E; e += stride) {
        int r = __builtin_nontemporal_load(&row[e]);
        atomicAdd(&deg[r], 1u);
    }
}

// ---------------------------------------------------------------------------
// 2a) Per-block exclusive scan of deg -> row_ptr (partial), block sums out.
// ---------------------------------------------------------------------------
__global__ void k_scan1(const unsigned int* __restrict__ deg, int* __restrict__ excl,
                        int* __restrict__ bsums, int n) {
    __shared__ int tmp[256];
    int tid = threadIdx.x;
    int i = blockIdx.x * 256 + tid;
    int v = (i < n) ? (int)deg[i] : 0;
    tmp[tid] = v;
    __syncthreads();
    for (int off = 1; off < 256; off <<= 1) {
        int t = (tid >= off) ? tmp[tid - off] : 0;
        __syncthreads();
        tmp[tid] += t;
        __syncthreads();
    }
    if (i < n) excl[i] = tmp[tid] - v;
    if (tid == 255) bsums[blockIdx.x] = tmp[255];
}

// ---------------------------------------------------------------------------
// 2b) Exclusive scan of block sums (single block; nb <= 512).
// ---------------------------------------------------------------------------
__global__ void k_scan2(int* __restrict__ bsums, int nb) {
    __shared__ int tmp[512];
    int tid = threadIdx.x;
    int v = (tid < nb) ? bsums[tid] : 0;
    tmp[tid] = v;
    __syncthreads();
    for (int off = 1; off < 512; off <<= 1) {
        int t = (tid >= off) ? tmp[tid - off] : 0;
        __syncthreads();
        tmp[tid] += t;
        __syncthreads();
    }
    if (tid < nb) bsums[tid] = tmp[tid] - v;
}

// ---------------------------------------------------------------------------
// 2c) Add block offsets; init cursor copy; dinv = rsqrt(deg+1).
// ---------------------------------------------------------------------------
__global__ void k_scan3(int* __restrict__ row_ptr, const int* __restrict__ bsums,
                        int* __restrict__ cursor, const unsigned int* __restrict__ deg,
                        float* __restrict__ dinv, int n, int E) {
    int i = blockIdx.x * 256 + threadIdx.x;
    if (i < n) {
        int rp = row_ptr[i] + bsums[i >> 8];
        row_ptr[i] = rp;
        cursor[i] = rp;
        dinv[i] = rsqrtf((float)(deg[i] + 1u));
    }
    if (i == 0) row_ptr[n] = E;
}

// ---------------------------------------------------------------------------
// 3) h[i][:] = bf16( dinv[i] * (x[i] @ W) ).  One wave computes FOUR rows
//    (shares each Ws read across 4 FMAs); lane j = output feature j.
//    W (32 KB) in LDS; x rows staged per-wave (wave64 lockstep, in-order LDS).
// ---------------------------------------------------------------------------
__global__ __launch_bounds__(256) void k_gemm(
    const float* __restrict__ x, const float* __restrict__ W,
    const float* __restrict__ dinv, unsigned short* __restrict__ h, int n) {
    __shared__ float Ws[D_IN * D_OUT];   // [k][j], 32 KB
    __shared__ float xs[4][4][D_IN];     // [wave][r][k], 8 KB
    for (int idx = threadIdx.x; idx < D_IN * D_OUT; idx += 256)
        Ws[idx] = W[idx];
    __syncthreads();

    const int wave = threadIdx.x >> 6;
    const int lane = threadIdx.x & 63;
    float* xw = &xs[wave][0][0];

    for (int i0 = (blockIdx.x * 4 + wave) * 4; i0 < n; i0 += gridDim.x * 16) {
#pragma unroll
        for (int r = 0; r < 4; ++r) {
            int i = min(i0 + r, n - 1);
            *(float2*)&xw[r * D_IN + lane * 2] =
                *(const float2*)&x[(size_t)i * D_IN + lane * 2];
        }
        float a0 = 0.f, a1 = 0.f, a2 = 0.f, a3 = 0.f;
#pragma unroll
        for (int k4 = 0; k4 < D_IN; k4 += 4) {
            float4 x0 = *(float4*)&xw[0 * D_IN + k4];
            float4 x1 = *(float4*)&xw[1 * D_IN + k4];
            float4 x2 = *(float4*)&xw[2 * D_IN + k4];
            float4 x3 = *(float4*)&xw[3 * D_IN + k4];
#pragma unroll
            for (int u = 0; u < 4; ++u) {
                float wv = Ws[(k4 + u) * D_OUT + lane];
                a0 = fmaf((&x0.x)[u], wv, a0);
                a1 = fmaf((&x1.x)[u], wv, a1);
                a2 = fmaf((&x2.x)[u], wv, a2);
                a3 = fmaf((&x3.x)[u], wv, a3);
            }
        }
        int nr = min(4, n - i0);
        if (nr == 4) {
            h[(size_t)(i0 + 0) * D_OUT + lane] = f2bf(dinv[i0 + 0] * a0);
            h[(size_t)(i0 + 1) * D_OUT + lane] = f2bf(dinv[i0 + 1] * a1);
            h[(size_t)(i0 + 2) * D_OUT + lane] = f2bf(dinv[i0 + 2] * a2);
            h[(size_t)(i0 + 3) * D_OUT + lane] = f2bf(dinv[i0 + 3] * a3);
        } else {
            for (int r = 0; r < nr; ++r) {
                float a = (r == 0) ? a0 : (r == 1) ? a1 : (r == 2) ? a2 : a3;
                h[(size_t)(i0 + r) * D_OUT + lane] = f2bf(dinv[i0 + r] * a);
            }
        }
    }
}

// ---------------------------------------------------------------------------
// 4) Counting-sort scatter, L2-write-combining version: 8 row-slices, each
//    slice-group (blockIdx & 7, ~XCD-aligned) scans the full edge list with
//    nontemporal loads and scatters only rows in its 1.6 MB scol window.
// ---------------------------------------------------------------------------
__global__ void k_bucket(const int* __restrict__ row, const int* __restrict__ col,
                         int* __restrict__ cursor, int* __restrict__ scol,
                         int E, int n) {
    const int slice = blockIdx.x & (NSLICE - 1);
    const int lo = (int)((long long)n * slice / NSLICE);
    const int hi = (int)((long long)n * (slice + 1) / NSLICE);
    const int gsz = (gridDim.x / NSLICE) * blockDim.x;
    int gid = (blockIdx.x / NSLICE) * blockDim.x + threadIdx.x;
    for (int e = gid; e < E; e += gsz) {
        int rw = __builtin_nontemporal_load(&row[e]);
        if (rw >= lo && rw < hi) {
            int c = __builtin_nontemporal_load(&col[e]);
            int pos = atomicAdd(&cursor[rw], 1);
            scol[pos] = c;
        }
    }
}

// ---------------------------------------------------------------------------
// 5) Gather-reduce + finalize: one wave per node, lane j = feature j.
//    out[i][j] = relu( dinv[i] * (h[i][j] + sum_c h[c][j]) + b[j] )
// ---------------------------------------------------------------------------
__global__ __launch_bounds__(256) void k_aggr(
    const unsigned short* __restrict__ h, const int* __restrict__ row_ptr,
    const int* __restrict__ scol, const float* __restrict__ dinv,
    const float* __restrict__ b, float* __restrict__ out, int n) {
    const int wave = threadIdx.x >> 6;
    const int lane = threadIdx.x & 63;
    const int i = blockIdx.x * 4 + wave;
    if (i >= n) return;

    float acc = bf2f(h[(size_t)i * D_OUT + lane]);  // self-loop term
    const int beg = row_ptr[i];
    const int end = row_ptr[i + 1];
    for (int base = beg; base < end; base += 64) {
        const int m = min(64, end - base);
        const int idx = base + ((lane < m) ? lane : 0);
        const int c = __builtin_nontemporal_load(&scol[idx]);
        int j = 0;
        for (; j + 8 <= m; j += 8) {
#pragma unroll
            for (int u = 0; u < 8; ++u) {
                int cj = __shfl(c, j + u);
                acc += bf2f(h[(size_t)cj * D_OUT + lane]);
            }
        }
        for (; j < m; ++j) {
            int cj = __shfl(c, j);
            acc += bf2f(h[(size_t)cj * D_OUT + lane]);
        }
    }
    out[(size_t)i * D_OUT + lane] = fmaxf(fmaf(dinv[i], acc, b[lane]), 0.f);
}

extern "C" void kernel_launch(void* const* d_in, const int* in_sizes, int n_in,
                              void* d_out, int out_size, void* d_ws, size_t ws_size,
                              hipStream_t stream) {
    const float* x  = (const float*)d_in[0];
    const int*   ei = (const int*)d_in[1];   // [2][E] int32: row=targets, col=sources
    const float* W  = (const float*)d_in[2];
    const float* b  = (const float*)d_in[3];
    const int n = in_sizes[0] / D_IN;   // 100000
    const int E = in_sizes[1] / 2;      // 3200000
    const int* row = ei;
    const int* col = ei + E;

    // workspace layout (64B-aligned chunks), total ~27 MB
    char* base = (char*)d_ws;
    size_t off = 0;
    auto alloc = [&](size_t bytes) { char* p = base + off; off += (bytes + 63) & ~(size_t)63; return p; };
    unsigned short* h       = (unsigned short*)alloc((size_t)n * D_OUT * 2); // 12.8 MB
    int*            scol    = (int*)alloc((size_t)E * 4);                    // 12.8 MB
    unsigned int*   deg     = (unsigned int*)alloc((size_t)n * 4);
    int*            row_ptr = (int*)alloc(((size_t)n + 1) * 4);
    int*            cursor  = (int*)alloc((size_t)n * 4);
    float*          dinv    = (float*)alloc((size_t)n * 4);
    int*            bsums   = (int*)alloc(512 * 4);

    const int NB = (n + 255) / 256;  // 391 <= 512

    hipMemsetAsync(deg, 0, (size_t)n * sizeof(unsigned int), stream);
    k_count<<<2048, 256, 0, stream>>>(row, deg, E);
    k_scan1<<<NB, 256, 0, stream>>>(deg, row_ptr, bsums, n);
    k_scan2<<<1, 512, 0, stream>>>(bsums, NB);
    k_scan3<<<NB, 256, 0, stream>>>(row_ptr, bsums, cursor, deg, dinv, n, E);
    k_gemm<<<2048, 256, 0, stream>>>(x, W, dinv, h, n);
    k_bucket<<<2048, 256, 0, stream>>>(row, col, cursor, scol, E, n);
    k_aggr<<<(n + 3) / 4, 256, 0, stream>>>(h, row_ptr, scol, dinv, b, (float*)d_out, n);
}